// Round 9
// baseline (316.125 us; speedup 1.0000x reference)
//
#include <hip/hip_runtime.h>
#include <hip/hip_fp16.h>

// APPNP encoder: e3 = ego + 0.9*A@(ego + 0.9*A@ego).
// R9: 3 kernels + 1 memset:
//  0. memset bcursor=0 (relative counts; slot base = bk*CAPB)
//  1. conv_scatter: fp32 ego -> fp16 table (fused chunk) + single-pass padded
//     bucket scatter (binary-search coalesced flush). NB=1563 buckets of 64 rows.
//  2. sort_spmm1: per-bucket 64-bin LDS counting sort -> row_start/row_end +
//     sorted ebuf, then fused pull spmm1 (edges L1/L2-hot), writes e2 fp16.
//     2x grid vs R8 (1563 blocks) fixes the 24% occupancy.
//  3. spmm2: pull SpMM from e2h -> fp32 out (nontemporal).

#define USER_NUM 60000
#define ITEM_NUM 40000
#define N_NODES  100000
#define EMB      64
#define NNZ      3200000
#define OMA      0.9f    // 1 - alpha
#define BR       64      // rows per bucket
#define NB       1563    // ceil(100000/64)
#define TILE     4096    // edges per scatter block
#define CAPB     2432    // padded slots per bucket (mean 2047, +8.5 sigma)

typedef float f32x4 __attribute__((ext_vector_type(4)));

// ---- 1) fused ego->fp16 conversion + single-pass bucket scatter ---------
// entry = (col | row_local<<17, val*0.9); slot base bk*CAPB, bcursor relative.
__global__ __launch_bounds__(256) void conv_scatter(const int* __restrict__ rows,
                                                    const int* __restrict__ cols,
                                                    const float* __restrict__ vals,
                                                    const float* __restrict__ ue,
                                                    const float* __restrict__ ie,
                                                    __half* __restrict__ ego_h,
                                                    int* __restrict__ bcursor,
                                                    int2* __restrict__ ebuf) {
    __shared__ int bins[NB + 1];   // hist, then exclusive offsets
    __shared__ int lcur[NB];       // binning cursors, then write-offset rebase
    __shared__ int wsum[4];
    __shared__ int2 stage[TILE];
    int t = threadIdx.x;
    int lane = t & 63, w = t >> 6;

    // --- conv chunk: 4 items of 8 floats each ---
    int gtid = blockIdx.x * 256 + t;
    const size_t usz = (size_t)USER_NUM * EMB;    // 3,840,000 (mult of 8)
#pragma unroll
    for (int q = 0; q < 4; ++q) {
        int it = gtid * 4 + q;
        if (it < N_NODES * EMB / 8) {
            size_t f0 = (size_t)it * 8;
            const float4* s4 = (f0 < usz) ? (const float4*)(ue + f0)
                                          : (const float4*)(ie + (f0 - usz));
            float4 x = s4[0], y = s4[1];
            union { float4 f4; __half2 h2[4]; } o;
            o.h2[0] = __floats2half2_rn(x.x, x.y);
            o.h2[1] = __floats2half2_rn(x.z, x.w);
            o.h2[2] = __floats2half2_rn(y.x, y.y);
            o.h2[3] = __floats2half2_rn(y.z, y.w);
            ((float4*)ego_h)[it] = o.f4;
        }
    }

    for (int b = t; b <= NB; b += 256) bins[b] = 0;
    __syncthreads();

    // load edges, histogram into bins
    int e0 = blockIdx.x * TILE;
    int mybk[16], mypk[16];
    float myv[16];
#pragma unroll
    for (int j = 0; j < 16; ++j) {
        int i = e0 + t + 256 * j;
        mybk[j] = -1;
        if (i < NNZ) {
            int r = rows[i], c = cols[i];
            myv[j]  = vals[i] * OMA;
            mybk[j] = r >> 6;
            mypk[j] = c | ((r & 63) << 17);
            atomicAdd(&bins[mybk[j]], 1);
        }
    }
    __syncthreads();

    // register scan: 7 bins/thread, wave shfl scan + cross-wave combine
    int b0 = t * 7;
    int rr[7];
    int s = 0;
#pragma unroll
    for (int q = 0; q < 7; ++q) {
        rr[q] = (b0 + q < NB) ? bins[b0 + q] : 0;
        s += rr[q];
    }
    int incl = s;
#pragma unroll
    for (int off = 1; off < 64; off <<= 1) {
        int v = __shfl_up(incl, off, 64);
        if (lane >= off) incl += v;
    }
    if (lane == 63) wsum[w] = incl;
    __syncthreads();
    int prefix = 0;
#pragma unroll
    for (int i = 0; i < 4; ++i) if (i < w) prefix += wsum[i];
    int excl = prefix + incl - s;
#pragma unroll
    for (int q = 0; q < 7; ++q) {
        int i = b0 + q;
        if (i < NB) { bins[i] = excl; lcur[i] = excl; excl += rr[q]; }
    }
    if (t == 255) bins[NB] = prefix + incl;   // total valid edges this tile
    __syncthreads();

    // bin into stage (bucket-sorted order)
#pragma unroll
    for (int j = 0; j < 16; ++j) {
        if (mybk[j] >= 0) {
            int p = atomicAdd(&lcur[mybk[j]], 1);
            stage[p] = make_int2(mypk[j], __float_as_int(myv[j]));
        }
    }
    __syncthreads();

    // Phase A: reserve global runs; lcur[b] := global write base - local_start
    for (int b = t; b < NB; b += 256) {
        int st = bins[b], en = bins[b + 1];
        int cnt = en - st;
        if (cnt > 0) lcur[b] = b * CAPB + atomicAdd(&bcursor[b], cnt) - st;
    }
    __syncthreads();

    // Phase B: lane-parallel coalesced flush (binary search bucket of entry i)
    int total = bins[NB];
    for (int i = t; i < total; i += 256) {
        int lo = 0, hi = NB;
        while (hi - lo > 1) {
            int mid = (lo + hi) >> 1;
            if (bins[mid] <= i) lo = mid; else hi = mid;
        }
        ebuf[(size_t)(lcur[lo] + i)] = stage[i];
    }
}

// ---- 2) per-bucket sort (64 bins) + fused spmm1 -------------------------
__global__ __launch_bounds__(256) void sort_spmm1(const int* __restrict__ bcursor,
                                                  int2* __restrict__ ebuf,
                                                  int* __restrict__ row_start,
                                                  int* __restrict__ row_end,
                                                  const __half* __restrict__ ego_h,
                                                  const float* __restrict__ ue,
                                                  const float* __restrict__ ie,
                                                  __half* __restrict__ e2h) {
    __shared__ int2 stage[CAPB];
    __shared__ int rhist[BR], rofs[BR], rcur[BR];
    int bk = blockIdx.x, t = threadIdx.x;
    int s = bk * CAPB;
    int cnt = min(bcursor[bk], CAPB);

    if (t < BR) rhist[t] = 0;
    __syncthreads();
    for (int i = t; i < cnt; i += 256) {
        int2 v = ebuf[(size_t)(s + i)];
        stage[i] = v;
        atomicAdd(&rhist[(v.x >> 17) & 63], 1);
    }
    __syncthreads();
    if (t < 64) {   // single-wave shfl scan, 1 bin/lane
        int h = rhist[t];
        int incl = h;
#pragma unroll
        for (int off = 1; off < 64; off <<= 1) {
            int v = __shfl_up(incl, off, 64);
            if (t >= off) incl += v;
        }
        int base = incl - h;
        rofs[t] = base;
        rcur[t] = base;
        int r = (bk << 6) + t;
        if (r < N_NODES) {
            row_start[r] = s + base;
            row_end[r]   = s + base + h;
        }
    }
    __syncthreads();
    // write row-sorted edges back (same L1/L2 region)
    for (int i = t; i < cnt; i += 256) {
        int2 v = stage[i];
        int p = atomicAdd(&rcur[(v.x >> 17) & 63], 1);
        ebuf[(size_t)(s + p)] = v;
    }
    __syncthreads();   // sorted edges visible block-wide

    // fused spmm1: 16 groups x 16 lanes; each group does 4 rows
    int lane  = t & 15;
    int qbase = (t & 63) & ~15;
    int g = t >> 4;
    const float2* srcv = (const float2*)ego_h;
#pragma unroll
    for (int q = 0; q < 4; ++q) {
        int rl = (g << 2) | q;
        int r  = (bk << 6) + rl;
        if (r >= N_NODES) break;
        const float* egop = (r < USER_NUM) ? (ue + (size_t)r * EMB)
                                           : (ie + (size_t)(r - USER_NUM) * EMB);
        float4 acc = ((const float4*)egop)[lane];
        int ss = s + rofs[rl];
        int ee = ss + rhist[rl];
        int2 cv = (ss + lane < ee) ? ebuf[(size_t)(ss + lane)] : make_int2(0, 0);
        for (int k = ss; k < ee; k += 16) {
            int idxn = k + 16 + lane;
            int2 nv = (idxn < ee) ? ebuf[(size_t)idxn] : make_int2(0, 0);
#pragma unroll
            for (int j = 0; j < 16; ++j) {
                int   cj = __shfl(cv.x, qbase + j, 64) & 0x1FFFF;
                float vj = __int_as_float(__shfl(cv.y, qbase + j, 64));
                union { float2 f2; __half2 h2[2]; } u;
                u.f2 = srcv[(size_t)cj * 16 + lane];
                float2 a = __half22float2(u.h2[0]);
                float2 b = __half22float2(u.h2[1]);
                acc.x += vj * a.x; acc.y += vj * a.y;
                acc.z += vj * b.x; acc.w += vj * b.y;
            }
            cv = nv;
        }
        union { float2 f2; __half2 h2[2]; } o;
        o.h2[0] = __floats2half2_rn(acc.x, acc.y);
        o.h2[1] = __floats2half2_rn(acc.z, acc.w);
        ((float2*)e2h)[(size_t)r * 16 + lane] = o.f2;
    }
}

// ---- 3) spmm2: pull from e2h, fp32 nontemporal out ----------------------
__global__ __launch_bounds__(256) void spmm2(const int* __restrict__ row_start,
                                             const int* __restrict__ row_end,
                                             const int2* __restrict__ colval,
                                             const __half* __restrict__ src,
                                             const float* __restrict__ ue,
                                             const float* __restrict__ ie,
                                             float* __restrict__ outb) {
    int tid = blockIdx.x * 256 + threadIdx.x;
    int r = tid >> 4;
    if (r >= N_NODES) return;
    int lane  = threadIdx.x & 15;
    int qbase = (threadIdx.x & 63) & ~15;

    const float* egop = (r < USER_NUM) ? (ue + (size_t)r * EMB)
                                       : (ie + (size_t)(r - USER_NUM) * EMB);
    float4 acc = ((const float4*)egop)[lane];
    const float2* srcv = (const float2*)src;
    int s = row_start[r], e = row_end[r];

    int2 cv = (s + lane < e) ? colval[(size_t)(s + lane)] : make_int2(0, 0);
    for (int k = s; k < e; k += 16) {
        int idxn = k + 16 + lane;
        int2 nv = (idxn < e) ? colval[(size_t)idxn] : make_int2(0, 0);
#pragma unroll
        for (int j = 0; j < 16; ++j) {
            int   cj = __shfl(cv.x, qbase + j, 64) & 0x1FFFF;
            float vj = __int_as_float(__shfl(cv.y, qbase + j, 64));
            union { float2 f2; __half2 h2[2]; } u;
            u.f2 = srcv[(size_t)cj * 16 + lane];
            float2 a = __half22float2(u.h2[0]);
            float2 b = __half22float2(u.h2[1]);
            acc.x += vj * a.x; acc.y += vj * a.y;
            acc.z += vj * b.x; acc.w += vj * b.y;
        }
        cv = nv;
    }
    f32x4 av = { acc.x, acc.y, acc.z, acc.w };
    __builtin_nontemporal_store(av, &((f32x4*)outb)[(size_t)r * 16 + lane]);
}

// ---- launch -------------------------------------------------------------
extern "C" void kernel_launch(void* const* d_in, const int* in_sizes, int n_in,
                              void* d_out, int out_size, void* d_ws, size_t ws_size,
                              hipStream_t stream) {
    const int*   rows = (const int*)d_in[0];
    const int*   cols = (const int*)d_in[1];
    const float* vals = (const float*)d_in[2];
    const float* ue   = (const float*)d_in[3];
    const float* ie   = (const float*)d_in[4];
    float* out = (float*)d_out;

    char* ws = (char*)d_ws;
    __half* ego_h    = (__half*)ws;                   // 12,800,000 B
    __half* e2h      = (__half*)(ws + 12800000);      // 12,800,000 B
    int2*   ebuf     = (int2*)(ws + 25600000);        // 1563*2432*8 = 30,409,728 B
    int*    row_s    = (int*)(ws + 56009728);         // 400,000 B
    int*    row_e    = (int*)(ws + 56409728);         // 400,000 B
    int*    bcursor  = (int*)(ws + 56809728);         // 6,252 B

    (void)hipMemsetAsync(bcursor, 0, NB * sizeof(int), stream);

    const int tiles = (NNZ + TILE - 1) / TILE;        // 782
    conv_scatter<<<tiles, 256, 0, stream>>>(rows, cols, vals, ue, ie,
                                            ego_h, bcursor, ebuf);
    sort_spmm1<<<NB, 256, 0, stream>>>(bcursor, ebuf, row_s, row_e,
                                       ego_h, ue, ie, e2h);

    const int spmmBlocks = (N_NODES * 16 + 255) / 256;  // 6250
    spmm2<<<spmmBlocks, 256, 0, stream>>>(row_s, row_e, ebuf, e2h, ue, ie, out);
}

// Round 10
// 304.442 us; speedup vs baseline: 1.0384x; 1.0384x over previous
//
#include <hip/hip_runtime.h>
#include <hip/hip_fp16.h>

// APPNP encoder: e3 = ego + 0.9*A@(ego + 0.9*A@ego).
// R10: R8 parameterization (BR=128, NB=782) + conv fused into scatter +
// col-slice-ordered counting sort (key = row_local*4 + col/25000) so both
// SpMM gathers sweep the fp16 table in 3.2 MB L2-resident slices.

#define USER_NUM 60000
#define ITEM_NUM 40000
#define N_NODES  100000
#define EMB      64
#define NNZ      3200000
#define OMA      0.9f    // 1 - alpha
#define BR       128     // rows per bucket
#define NB       782     // ceil(100000/128)
#define TILE     4096    // edges per scatter block
#define CAPB     4480    // padded slots per bucket (mean 4096, +6 sigma)
#define NKEY     512     // BR * 4 slices

typedef float f32x4 __attribute__((ext_vector_type(4)));

// ---- 1) fused ego->fp16 conversion + single-pass bucket scatter ---------
// entry = (col | row_local<<17, val*0.9); slot base bk*CAPB, bcursor relative.
__global__ __launch_bounds__(256) void conv_scatter(const int* __restrict__ rows,
                                                    const int* __restrict__ cols,
                                                    const float* __restrict__ vals,
                                                    const float* __restrict__ ue,
                                                    const float* __restrict__ ie,
                                                    __half* __restrict__ ego_h,
                                                    int* __restrict__ bcursor,
                                                    int2* __restrict__ ebuf) {
    __shared__ int bins[NB + 1];   // hist, then exclusive offsets
    __shared__ int lcur[NB];       // binning cursors, then write-offset rebase
    __shared__ int wsum[4];
    __shared__ int2 stage[TILE];
    int t = threadIdx.x;
    int lane = t & 63, w = t >> 6;

    // --- conv chunk: 4 items of 8 floats each (3200 threads-blocks cover) ---
    int gtid = blockIdx.x * 256 + t;
    const size_t usz = (size_t)USER_NUM * EMB;    // 3,840,000 (mult of 8)
#pragma unroll
    for (int q = 0; q < 4; ++q) {
        int it = gtid * 4 + q;
        if (it < N_NODES * EMB / 8) {
            size_t f0 = (size_t)it * 8;
            const float4* s4 = (f0 < usz) ? (const float4*)(ue + f0)
                                          : (const float4*)(ie + (f0 - usz));
            float4 x = s4[0], y = s4[1];
            union { float4 f4; __half2 h2[4]; } o;
            o.h2[0] = __floats2half2_rn(x.x, x.y);
            o.h2[1] = __floats2half2_rn(x.z, x.w);
            o.h2[2] = __floats2half2_rn(y.x, y.y);
            o.h2[3] = __floats2half2_rn(y.z, y.w);
            ((float4*)ego_h)[it] = o.f4;
        }
    }

    for (int b = t; b <= NB; b += 256) bins[b] = 0;
    __syncthreads();

    // load edges, histogram into bins
    int e0 = blockIdx.x * TILE;
    int mybk[16], mypk[16];
    float myv[16];
#pragma unroll
    for (int j = 0; j < 16; ++j) {
        int i = e0 + t + 256 * j;
        mybk[j] = -1;
        if (i < NNZ) {
            int r = rows[i], c = cols[i];
            myv[j]  = vals[i] * OMA;
            mybk[j] = r >> 7;
            mypk[j] = c | ((r & 127) << 17);
            atomicAdd(&bins[mybk[j]], 1);
        }
    }
    __syncthreads();

    // register scan: 4 bins/thread, wave shfl scan + cross-wave combine
    int b0 = t * 4;
    int r0 = (b0     < NB) ? bins[b0]     : 0;
    int r1 = (b0 + 1 < NB) ? bins[b0 + 1] : 0;
    int r2 = (b0 + 2 < NB) ? bins[b0 + 2] : 0;
    int r3 = (b0 + 3 < NB) ? bins[b0 + 3] : 0;
    int s = r0 + r1 + r2 + r3;
    int incl = s;
#pragma unroll
    for (int off = 1; off < 64; off <<= 1) {
        int v = __shfl_up(incl, off, 64);
        if (lane >= off) incl += v;
    }
    if (lane == 63) wsum[w] = incl;
    __syncthreads();
    int prefix = 0;
#pragma unroll
    for (int i = 0; i < 4; ++i) if (i < w) prefix += wsum[i];
    int excl = prefix + incl - s;
    if (b0     < NB) { bins[b0]     = excl; lcur[b0]     = excl; excl += r0; }
    if (b0 + 1 < NB) { bins[b0 + 1] = excl; lcur[b0 + 1] = excl; excl += r1; }
    if (b0 + 2 < NB) { bins[b0 + 2] = excl; lcur[b0 + 2] = excl; excl += r2; }
    if (b0 + 3 < NB) { bins[b0 + 3] = excl; lcur[b0 + 3] = excl; excl += r3; }
    if (t == 255) bins[NB] = prefix + incl;   // total valid edges this tile
    __syncthreads();

    // bin into stage (bucket-sorted order)
#pragma unroll
    for (int j = 0; j < 16; ++j) {
        if (mybk[j] >= 0) {
            int p = atomicAdd(&lcur[mybk[j]], 1);
            stage[p] = make_int2(mypk[j], __float_as_int(myv[j]));
        }
    }
    __syncthreads();

    // Phase A: reserve global runs; lcur[b] := global write base - local_start
    for (int b = t; b < NB; b += 256) {
        int st = bins[b], en = bins[b + 1];
        int cnt = en - st;
        if (cnt > 0) lcur[b] = b * CAPB + atomicAdd(&bcursor[b], cnt) - st;
    }
    __syncthreads();

    // Phase B: lane-parallel coalesced flush (binary search bucket of entry i)
    int total = bins[NB];
    for (int i = t; i < total; i += 256) {
        int lo = 0, hi = NB;
        while (hi - lo > 1) {
            int mid = (lo + hi) >> 1;
            if (bins[mid] <= i) lo = mid; else hi = mid;
        }
        ebuf[(size_t)(lcur[lo] + i)] = stage[i];
    }
}

// ---- 2) per-bucket (row,slice) counting sort + fused spmm1 --------------
// key = row_local*4 + col/25000  ->  edges slice-ordered within each row.
__global__ __launch_bounds__(256) void sort_spmm1(const int* __restrict__ bcursor,
                                                  int2* __restrict__ ebuf,
                                                  int* __restrict__ row_start,
                                                  int* __restrict__ row_end,
                                                  const __half* __restrict__ ego_h,
                                                  const float* __restrict__ ue,
                                                  const float* __restrict__ ie,
                                                  __half* __restrict__ e2h) {
    __shared__ int    pkbuf[CAPB];     // 17.9 KB
    __shared__ __half valbuf[CAPB];    // 9.0 KB
    __shared__ int rhist[NKEY], rofs[NKEY], rcur[NKEY];  // 6.1 KB
    __shared__ int wsum[4];
    int bk = blockIdx.x, t = threadIdx.x;
    int lane = t & 63, w = t >> 6;
    int s = bk * CAPB;
    int cnt = min(bcursor[bk], CAPB);

    for (int b = t; b < NKEY; b += 256) rhist[b] = 0;
    __syncthreads();
    for (int i = t; i < cnt; i += 256) {
        int2 v = ebuf[(size_t)(s + i)];
        pkbuf[i]  = v.x;
        valbuf[i] = __float2half(__int_as_float(v.y));
        int c  = v.x & 0x1FFFF;
        int sl = (c >= 25000) + (c >= 50000) + (c >= 75000);
        int key = (((v.x >> 17) & 127) << 2) | sl;
        atomicAdd(&rhist[key], 1);
    }
    __syncthreads();

    // scan 512 bins: 2/thread, wave shfl scan + cross-wave combine
    int b0 = t * 2;
    int h0 = rhist[b0], h1 = rhist[b0 + 1];
    int ss2 = h0 + h1;
    int incl = ss2;
#pragma unroll
    for (int off = 1; off < 64; off <<= 1) {
        int v = __shfl_up(incl, off, 64);
        if (lane >= off) incl += v;
    }
    if (lane == 63) wsum[w] = incl;
    __syncthreads();
    int prefix = 0;
#pragma unroll
    for (int i = 0; i < 4; ++i) if (i < w) prefix += wsum[i];
    int excl = prefix + incl - ss2;
    rofs[b0] = excl;     rcur[b0] = excl;
    rofs[b0 + 1] = excl + h0; rcur[b0 + 1] = excl + h0;
    __syncthreads();

    // row ranges (row rl occupies keys [4rl, 4rl+3], contiguous)
    if (t < BR) {
        int r = (bk << 7) + t;
        if (r < N_NODES) {
            int st = rofs[t << 2];
            int en = rofs[t << 2] + rhist[t << 2] + rhist[(t << 2) + 1]
                   + rhist[(t << 2) + 2] + rhist[(t << 2) + 3];
            row_start[r] = s + st;
            row_end[r]   = s + en;
        }
    }
    // sorted writeback (L2-local region)
    for (int i = t; i < cnt; i += 256) {
        int pk = pkbuf[i];
        int c  = pk & 0x1FFFF;
        int sl = (c >= 25000) + (c >= 50000) + (c >= 75000);
        int key = (((pk >> 17) & 127) << 2) | sl;
        int p = atomicAdd(&rcur[key], 1);
        ebuf[(size_t)(s + p)] = make_int2(pk, __float_as_int(__half2float(valbuf[i])));
    }
    __syncthreads();   // sorted edges visible block-wide

    // fused spmm1: 16 groups x 16 lanes; each group does 8 rows
    int l16   = t & 15;
    int qbase = (t & 63) & ~15;
    int g = t >> 4;
    const float2* srcv = (const float2*)ego_h;
#pragma unroll
    for (int rr = 0; rr < 8; ++rr) {
        int rl = (g << 3) | rr;
        int r  = (bk << 7) + rl;
        if (r >= N_NODES) break;
        const float* egop = (r < USER_NUM) ? (ue + (size_t)r * EMB)
                                           : (ie + (size_t)(r - USER_NUM) * EMB);
        float4 acc = ((const float4*)egop)[l16];
        int ss = s + rofs[rl << 2];
        int ee = s + rofs[rl << 2] + rhist[rl << 2] + rhist[(rl << 2) + 1]
               + rhist[(rl << 2) + 2] + rhist[(rl << 2) + 3];
        int2 cv = (ss + l16 < ee) ? ebuf[(size_t)(ss + l16)] : make_int2(0, 0);
        for (int k = ss; k < ee; k += 16) {
            int idxn = k + 16 + l16;
            int2 nv = (idxn < ee) ? ebuf[(size_t)idxn] : make_int2(0, 0);
#pragma unroll
            for (int j = 0; j < 16; ++j) {
                int   cj = __shfl(cv.x, qbase + j, 64) & 0x1FFFF;
                float vj = __int_as_float(__shfl(cv.y, qbase + j, 64));
                union { float2 f2; __half2 h2[2]; } u;
                u.f2 = srcv[(size_t)cj * 16 + l16];
                float2 a = __half22float2(u.h2[0]);
                float2 b = __half22float2(u.h2[1]);
                acc.x += vj * a.x; acc.y += vj * a.y;
                acc.z += vj * b.x; acc.w += vj * b.y;
            }
            cv = nv;
        }
        union { float2 f2; __half2 h2[2]; } o;
        o.h2[0] = __floats2half2_rn(acc.x, acc.y);
        o.h2[1] = __floats2half2_rn(acc.z, acc.w);
        ((float2*)e2h)[(size_t)r * 16 + l16] = o.f2;
    }
}

// ---- 3) spmm2: pull from e2h, fp32 nontemporal out ----------------------
__global__ __launch_bounds__(256) void spmm2(const int* __restrict__ row_start,
                                             const int* __restrict__ row_end,
                                             const int2* __restrict__ colval,
                                             const __half* __restrict__ src,
                                             const float* __restrict__ ue,
                                             const float* __restrict__ ie,
                                             float* __restrict__ outb) {
    int tid = blockIdx.x * 256 + threadIdx.x;
    int r = tid >> 4;
    if (r >= N_NODES) return;
    int lane  = threadIdx.x & 15;
    int qbase = (threadIdx.x & 63) & ~15;

    const float* egop = (r < USER_NUM) ? (ue + (size_t)r * EMB)
                                       : (ie + (size_t)(r - USER_NUM) * EMB);
    float4 acc = ((const float4*)egop)[lane];
    const float2* srcv = (const float2*)src;
    int s = row_start[r], e = row_end[r];

    int2 cv = (s + lane < e) ? colval[(size_t)(s + lane)] : make_int2(0, 0);
    for (int k = s; k < e; k += 16) {
        int idxn = k + 16 + lane;
        int2 nv = (idxn < e) ? colval[(size_t)idxn] : make_int2(0, 0);
#pragma unroll
        for (int j = 0; j < 16; ++j) {
            int   cj = __shfl(cv.x, qbase + j, 64) & 0x1FFFF;
            float vj = __int_as_float(__shfl(cv.y, qbase + j, 64));
            union { float2 f2; __half2 h2[2]; } u;
            u.f2 = srcv[(size_t)cj * 16 + lane];
            float2 a = __half22float2(u.h2[0]);
            float2 b = __half22float2(u.h2[1]);
            acc.x += vj * a.x; acc.y += vj * a.y;
            acc.z += vj * b.x; acc.w += vj * b.y;
        }
        cv = nv;
    }
    f32x4 av = { acc.x, acc.y, acc.z, acc.w };
    __builtin_nontemporal_store(av, &((f32x4*)outb)[(size_t)r * 16 + lane]);
}

// ---- launch -------------------------------------------------------------
extern "C" void kernel_launch(void* const* d_in, const int* in_sizes, int n_in,
                              void* d_out, int out_size, void* d_ws, size_t ws_size,
                              hipStream_t stream) {
    const int*   rows = (const int*)d_in[0];
    const int*   cols = (const int*)d_in[1];
    const float* vals = (const float*)d_in[2];
    const float* ue   = (const float*)d_in[3];
    const float* ie   = (const float*)d_in[4];
    float* out = (float*)d_out;

    char* ws = (char*)d_ws;
    __half* ego_h    = (__half*)ws;                   // 12,800,000 B
    __half* e2h      = (__half*)(ws + 12800000);      // 12,800,000 B
    int2*   ebuf     = (int2*)(ws + 25600000);        // 782*4480*8 = 28,026,880 B
    int*    row_s    = (int*)(ws + 53626880);         // 400,000 B
    int*    row_e    = (int*)(ws + 54026880);         // 400,000 B
    int*    bcursor  = (int*)(ws + 54426880);         // 3,128 B

    (void)hipMemsetAsync(bcursor, 0, NB * sizeof(int), stream);

    const int tiles = (NNZ + TILE - 1) / TILE;        // 782
    conv_scatter<<<tiles, 256, 0, stream>>>(rows, cols, vals, ue, ie,
                                            ego_h, bcursor, ebuf);
    sort_spmm1<<<NB, 256, 0, stream>>>(bcursor, ebuf, row_s, row_e,
                                       ego_h, ue, ie, e2h);

    const int spmmBlocks = (N_NODES * 16 + 255) / 256;  // 6250
    spmm2<<<spmmBlocks, 256, 0, stream>>>(row_s, row_e, ebuf, e2h, ue, ie, out);
}